// Round 1
// baseline (737.723 us; speedup 1.0000x reference)
//
#include <hip/hip_runtime.h>

#define B_ 8
#define S_ 4096
#define IN_ 64
#define HID_ 512
#define NSTEP 12
#define SP_ (S_ + 2)
#define NP_ (B_ * SP_)
#define NTOT (B_ * S_)

typedef unsigned short u16;
typedef __attribute__((ext_vector_type(8))) short bf16x8;
typedef __attribute__((ext_vector_type(4))) float f32x4;

__device__ __forceinline__ u16 f2bf(float f) {
  unsigned u = __float_as_uint(f);
  u += 0x7fffu + ((u >> 16) & 1u);
  return (u16)(u >> 16);
}

__device__ __forceinline__ void gload16(const void* g, void* l) {
  __builtin_amdgcn_global_load_lds((const __attribute__((address_space(1))) void*)g,
                                   (__attribute__((address_space(3))) void*)l, 16, 0, 0);
}

// ---------------- setup: bf16 conversions + weight transposes + pad-row zeroing ----------------
__global__ void setup_kernel(const float* __restrict__ x, const float* __restrict__ Wc,
                             const float* __restrict__ Wi, const float* __restrict__ Wo,
                             u16* __restrict__ wcb, u16* __restrict__ wib,
                             u16* __restrict__ wob, u16* __restrict__ xbf,
                             u16* __restrict__ h0, u16* __restrict__ h1) {
  const int n_wc = 3 * HID_ * HID_;       // wcb[k][o][i] = Wc[o][i][k]
  const int n_wio = IN_ * HID_;
  const int n_xb = NTOT * IN_;
  const int n_pad = 2 * B_ * 2 * HID_;
  const long total = (long)n_wc + 2 * n_wio + n_xb + n_pad;
  for (long u = (long)blockIdx.x * blockDim.x + threadIdx.x; u < total;
       u += (long)gridDim.x * blockDim.x) {
    long v = u;
    if (v < n_wc) {
      int k = (int)(v / (HID_ * HID_));
      int rem = (int)(v % (HID_ * HID_));
      int o = rem / HID_, i = rem % HID_;
      wcb[v] = f2bf(Wc[((long)o * HID_ + i) * 3 + k]);
    } else if ((v -= n_wc) < n_wio) {      // wib[i][j] = Wi[j][i]
      int i = (int)(v / IN_), j = (int)(v % IN_);
      wib[v] = f2bf(Wi[j * HID_ + i]);
    } else if ((v -= n_wio) < n_wio) {     // wob[j][i] = Wo[i][j]
      int j = (int)(v / HID_), i = (int)(v % HID_);
      wob[v] = f2bf(Wo[i * IN_ + j]);
    } else if ((v -= n_wio) < n_xb) {
      xbf[v] = f2bf(x[v]);
    } else {
      v -= n_xb;                           // zero pad rows (s=-1 and s=S per batch, both buffers)
      int buf = (int)(v / (B_ * 2 * HID_));
      int r = (int)(v % (B_ * 2 * HID_));
      int b = r / (2 * HID_);
      int q = r % (2 * HID_);
      int side = q / HID_, i = q % HID_;
      long p = (long)b * SP_ + (side ? (S_ + 1) : 0);
      (buf ? h1 : h0)[p * HID_ + i] = 0;
    }
  }
}

// ---------------- proj_in: h0[n][i] = x[n][:] @ W_in[:,i] + b_in  (bf16 MFMA, K=64) ----------------
__global__ __launch_bounds__(256, 2) void proj_in_gemm(const u16* __restrict__ xb,
                                                       const u16* __restrict__ wib,
                                                       const float* __restrict__ bin,
                                                       u16* __restrict__ hout) {
  __shared__ __align__(16) u16 Ab[128 * 64];
  __shared__ __align__(16) u16 Bb[128 * 64];
  const int tid = threadIdx.x, wid = tid >> 6, lane = tid & 63;
  const int nt = blockIdx.x, mt = blockIdx.y;
  const int wr = wid >> 1, wcn = wid & 1, fr = lane & 15, fq = lane >> 4;
#pragma unroll
  for (int c = 0; c < 4; ++c) {
    const int ch = wid * 4 + c;
    const int row = ch * 8 + (lane >> 3), cb = (lane & 7) * 8;
    gload16(wib + (mt * 128 + row) * 64 + cb, &Ab[ch * 512]);
    gload16(xb + ((long)nt * 128 + row) * 64 + cb, &Bb[ch * 512]);
  }
  f32x4 acc[4][4];
#pragma unroll
  for (int m = 0; m < 4; ++m)
#pragma unroll
    for (int n = 0; n < 4; ++n) acc[m][n] = {0.f, 0.f, 0.f, 0.f};
  __syncthreads();
#pragma unroll
  for (int t = 0; t < 2; ++t) {
    const int j0 = t * 32;
    bf16x8 af[4], bfv[4];
#pragma unroll
    for (int m = 0; m < 4; ++m)
      af[m] = *(const bf16x8*)&Ab[(wr * 64 + m * 16 + fr) * 64 + j0 + fq * 8];
#pragma unroll
    for (int n = 0; n < 4; ++n)
      bfv[n] = *(const bf16x8*)&Bb[(wcn * 64 + n * 16 + fr) * 64 + j0 + fq * 8];
#pragma unroll
    for (int m = 0; m < 4; ++m)
#pragma unroll
      for (int n = 0; n < 4; ++n)
        acc[m][n] = __builtin_amdgcn_mfma_f32_16x16x32_bf16(af[m], bfv[n], acc[m][n], 0, 0, 0);
  }
  const int n0 = nt * 128;
  const int bb = n0 / S_, s0v = n0 % S_;
  const int prow = bb * SP_ + s0v + 1;
#pragma unroll
  for (int m = 0; m < 4; ++m) {
    const int i = mt * 128 + wr * 64 + m * 16 + fq * 4;
    const float4 bias = *(const float4*)&bin[i];
#pragma unroll
    for (int n = 0; n < 4; ++n) {
      const int nl = wcn * 64 + n * 16 + fr;
      const long p = prow + nl;
      union { u16 q[4]; uint2 v; } u;
      u.q[0] = f2bf(acc[m][n][0] + bias.x);
      u.q[1] = f2bf(acc[m][n][1] + bias.y);
      u.q[2] = f2bf(acc[m][n][2] + bias.z);
      u.q[3] = f2bf(acc[m][n][3] + bias.w);
      *(uint2*)&hout[p * HID_ + i] = u.v;
    }
  }
}

// ---------------- conv step: c[o,n] = sum_{k,i} W[o,i,k] h[i,n+k-1]; relu; bf16 out ----------------
__global__ __launch_bounds__(256, 2) void conv_gemm(const u16* __restrict__ hin,
                                                    u16* __restrict__ hout,
                                                    const u16* __restrict__ wcb,
                                                    const float* __restrict__ bconv) {
  __shared__ __align__(16) u16 Ab[2][128 * 32];   // [o][i]
  __shared__ __align__(16) u16 Bb[2][128 * 32];   // [n][i]
  const int tid = threadIdx.x;
  const int wid = tid >> 6, lane = tid & 63;
  const int nt = blockIdx.x, mt = blockIdx.y;
  const int bb = (nt * 128) / S_, s0 = (nt * 128) % S_;
  const int prow0 = bb * SP_ + s0;                // tap-k tile rows start at prow0+k
  const int l4 = lane >> 2, lb = (lane & 3) * 8;
  const int wr = wid >> 1, wcn = wid & 1;
  const int fr = lane & 15, fq = lane >> 4;

  f32x4 acc[4][4];
#pragma unroll
  for (int m = 0; m < 4; ++m)
#pragma unroll
    for (int n = 0; n < 4; ++n) acc[m][n] = {0.f, 0.f, 0.f, 0.f};

  auto stage = [&](int buf, int t) {
    const int k = t % 3, i0 = (t / 3) * 32;       // i-outer, tap-inner: shifted B re-reads hit L1/L2
#pragma unroll
    for (int c = 0; c < 2; ++c) {
      const int ch = wid * 2 + c;
      const int row = ch * 16 + l4;
      gload16(wcb + ((k * HID_ + mt * 128 + row) * HID_ + i0 + lb), &Ab[buf][ch * 512]);
      gload16(hin + (long)(prow0 + k + row) * HID_ + i0 + lb, &Bb[buf][ch * 512]);
    }
  };

  stage(0, 0);
  __syncthreads();
  for (int t = 0; t < 48; ++t) {
    const int cur = t & 1;
    if (t < 47) stage(cur ^ 1, t + 1);
    bf16x8 af[4], bfv[4];
#pragma unroll
    for (int m = 0; m < 4; ++m)
      af[m] = *(const bf16x8*)&Ab[cur][(wr * 64 + m * 16 + fr) * 32 + fq * 8];
#pragma unroll
    for (int n = 0; n < 4; ++n)
      bfv[n] = *(const bf16x8*)&Bb[cur][(wcn * 64 + n * 16 + fr) * 32 + fq * 8];
#pragma unroll
    for (int m = 0; m < 4; ++m)
#pragma unroll
      for (int n = 0; n < 4; ++n)
        acc[m][n] = __builtin_amdgcn_mfma_f32_16x16x32_bf16(af[m], bfv[n], acc[m][n], 0, 0, 0);
    __syncthreads();
  }
#pragma unroll
  for (int m = 0; m < 4; ++m) {
    const int o = mt * 128 + wr * 64 + m * 16 + fq * 4;
    const float4 bias = *(const float4*)&bconv[o];
#pragma unroll
    for (int n = 0; n < 4; ++n) {
      const int nl = wcn * 64 + n * 16 + fr;
      const long p = (long)prow0 + 1 + nl;
      union { u16 q[4]; uint2 v; } u;
      u.q[0] = f2bf(fmaxf(acc[m][n][0] + bias.x, 0.f));
      u.q[1] = f2bf(fmaxf(acc[m][n][1] + bias.y, 0.f));
      u.q[2] = f2bf(fmaxf(acc[m][n][2] + bias.z, 0.f));
      u.q[3] = f2bf(fmaxf(acc[m][n][3] + bias.w, 0.f));
      *(uint2*)&hout[p * HID_ + o] = u.v;
    }
  }
}

// ---------------- proj_out: out[n][j] = h[n][:] @ W_out[:,j] + b_out (fp32 out) ----------------
__global__ __launch_bounds__(256, 2) void proj_out_gemm(const u16* __restrict__ hin,
                                                        const u16* __restrict__ wob,
                                                        const float* __restrict__ bout,
                                                        float* __restrict__ out) {
  __shared__ __align__(16) u16 Ab[2][128 * 32];   // [n][i]
  __shared__ __align__(16) u16 Bb[2][64 * 32];    // [j][i]
  const int tid = threadIdx.x, wid = tid >> 6, lane = tid & 63;
  const int nt = blockIdx.x;
  const int bb = (nt * 128) / S_, s0v = (nt * 128) % S_;
  const int prow0 = bb * SP_ + s0v + 1;
  const int l4 = lane >> 2, lb = (lane & 3) * 8;
  const int fr = lane & 15, fq = lane >> 4;

  f32x4 acc[2][4];
#pragma unroll
  for (int m = 0; m < 2; ++m)
#pragma unroll
    for (int n = 0; n < 4; ++n) acc[m][n] = {0.f, 0.f, 0.f, 0.f};

  auto stage = [&](int buf, int t) {
    const int i0 = t * 32;
#pragma unroll
    for (int c = 0; c < 2; ++c) {
      const int ch = wid * 2 + c;
      gload16(hin + (long)(prow0 + ch * 16 + l4) * HID_ + i0 + lb, &Ab[buf][ch * 512]);
    }
    gload16(wob + (wid * 16 + l4) * HID_ + i0 + lb, &Bb[buf][wid * 512]);
  };

  stage(0, 0);
  __syncthreads();
  for (int t = 0; t < 16; ++t) {
    const int cur = t & 1;
    if (t < 15) stage(cur ^ 1, t + 1);
    bf16x8 af[2], bfv[4];
#pragma unroll
    for (int m = 0; m < 2; ++m)
      af[m] = *(const bf16x8*)&Ab[cur][(wid * 32 + m * 16 + fr) * 32 + fq * 8];
#pragma unroll
    for (int j = 0; j < 4; ++j)
      bfv[j] = *(const bf16x8*)&Bb[cur][(j * 16 + fr) * 32 + fq * 8];
#pragma unroll
    for (int m = 0; m < 2; ++m)
#pragma unroll
      for (int j = 0; j < 4; ++j)
        acc[m][j] = __builtin_amdgcn_mfma_f32_16x16x32_bf16(af[m], bfv[j], acc[m][j], 0, 0, 0);
    __syncthreads();
  }
  const int n0 = nt * 128;
#pragma unroll
  for (int m = 0; m < 2; ++m) {
    const int nbase = n0 + wid * 32 + m * 16 + fq * 4;
#pragma unroll
    for (int jf = 0; jf < 4; ++jf) {
      const int j = jf * 16 + fr;
      const float bj = bout[j];
#pragma unroll
      for (int r = 0; r < 4; ++r)
        out[(long)(nbase + r) * IN_ + j] = acc[m][jf][r] + bj;
    }
  }
}

extern "C" void kernel_launch(void* const* d_in, const int* in_sizes, int n_in,
                              void* d_out, int out_size, void* d_ws, size_t ws_size,
                              hipStream_t stream) {
  (void)in_sizes; (void)n_in; (void)out_size; (void)ws_size;
  const float* x = (const float*)d_in[0];
  const float* W_in = (const float*)d_in[1];
  const float* b_in = (const float*)d_in[2];
  const float* W_conv = (const float*)d_in[3];
  const float* b_conv = (const float*)d_in[4];
  const float* W_out = (const float*)d_in[5];
  const float* b_out = (const float*)d_in[6];
  float* out = (float*)d_out;
  char* ws = (char*)d_ws;

  const size_t hbytes = (size_t)NP_ * HID_ * sizeof(u16);        // 33,570,816 B
  u16* h0 = (u16*)ws;
  u16* h1 = (u16*)(ws + hbytes);
  u16* wcb = (u16*)(ws + 2 * hbytes);
  u16* wib = (u16*)(ws + 2 * hbytes + (size_t)3 * HID_ * HID_ * 2);
  u16* wob = (u16*)(ws + 2 * hbytes + ((size_t)3 * HID_ * HID_ + IN_ * HID_) * 2);
  u16* xbf = (u16*)(ws + 2 * hbytes + ((size_t)3 * HID_ * HID_ + 2 * IN_ * HID_) * 2);

  setup_kernel<<<2048, 256, 0, stream>>>(x, W_conv, W_in, W_out, wcb, wib, wob, xbf, h0, h1);
  proj_in_gemm<<<dim3(NTOT / 128, HID_ / 128), 256, 0, stream>>>(xbf, wib, b_in, h0);
  const u16* cin = h0;
  u16* cout = h1;
  for (int s = 0; s < NSTEP; ++s) {
    conv_gemm<<<dim3(NTOT / 128, HID_ / 128), 256, 0, stream>>>(cin, cout, wcb, b_conv);
    u16* t = (u16*)cin; cin = cout; cout = t;
  }
  proj_out_gemm<<<NTOT / 128, 256, 0, stream>>>(cin, wob, b_out, out);
}